// Round 2
// baseline (1691.659 us; speedup 1.0000x reference)
//
#include <hip/hip_runtime.h>
#include <stdint.h>

#define B_ 16
#define V_ 40000
#define C_ 128
#define H_ 56
#define W_ 56
#define E_ 120000
#define M_ (V_*B_)   // 640000 rows

typedef float f32x4 __attribute__((ext_vector_type(4)));
typedef __bf16 bf16x8 __attribute__((ext_vector_type(8)));

// Big scratch in device globals (fully rewritten every call; no cross-call state).
__device__ __align__(16) uint16_t g_bufA[(size_t)M_*C_];   // g, then t  (bf16, [V,B,C])
__device__ __align__(16) uint16_t g_bufB[(size_t)M_*C_];   // z (aggregated neighbors)
__device__ __align__(16) uint16_t g_bufD[(size_t)M_*C_];   // d (conv1 out, residual)
__device__ __align__(16) uint16_t g_bhwc[(size_t)B_*H_*W_*C_]; // img feats -> [B,H,W,C] bf16
__device__ __align__(16) uint16_t g_wf[6][C_*C_];          // frag-ordered weights (A-operand)
__device__ int g_cnt[V_];
__device__ int g_rowptr[V_+1];
__device__ int g_cursor[V_];
__device__ int g_adj[2*E_];

__device__ inline float bf_lo(uint32_t u){ return __builtin_bit_cast(float, u<<16); }
__device__ inline float bf_hi(uint32_t u){ return __builtin_bit_cast(float, u & 0xffff0000u); }
__device__ inline uint32_t f2bf(float f){ uint32_t u = __builtin_bit_cast(uint32_t,f); return (u + 0x7fffu + ((u>>16)&1u))>>16; }
__device__ inline uint32_t pk2(float lo, float hi){ return f2bf(lo) | (f2bf(hi)<<16); }

__device__ inline uint16_t* big_buf(int s){ return s==0 ? g_bufA : (s==1 ? g_bufB : g_bufD); }

// ---------------- CSR build ----------------
__global__ void k_zero(){
  int i = blockIdx.x*256 + threadIdx.x;
  if (i < V_) g_cnt[i] = 0;
}
__global__ void k_count(const int* __restrict__ ed){
  int e = blockIdx.x*256 + threadIdx.x;
  if (e < E_){
    atomicAdd(&g_cnt[ed[2*e]],1);
    atomicAdd(&g_cnt[ed[2*e+1]],1);
  }
}
__global__ __launch_bounds__(1024) void k_scan(){
  __shared__ int sd[1024];
  __shared__ int s_carry;
  if (threadIdx.x==0) s_carry = 0;
  __syncthreads();
  for (int base=0; base<V_; base+=1024){
    int idx = base + (int)threadIdx.x;
    int vl = (idx<V_)? g_cnt[idx] : 0;
    sd[threadIdx.x] = vl;
    __syncthreads();
    for (int off=1; off<1024; off<<=1){
      int t = 0;
      if ((int)threadIdx.x >= off) t = sd[threadIdx.x-off];
      __syncthreads();
      sd[threadIdx.x] += t;
      __syncthreads();
    }
    int excl = sd[threadIdx.x] - vl + s_carry;
    if (idx<V_){ g_rowptr[idx] = excl; g_cursor[idx] = excl; }
    __syncthreads();
    if (threadIdx.x==0) s_carry += sd[1023];
    __syncthreads();
  }
  if (threadIdx.x==0) g_rowptr[V_] = s_carry;
}
__global__ void k_fill(const int* __restrict__ ed){
  int e = blockIdx.x*256 + threadIdx.x;
  if (e < E_){
    int i = ed[2*e], j = ed[2*e+1];
    int p = atomicAdd(&g_cursor[i],1); g_adj[p] = j;
    int q = atomicAdd(&g_cursor[j],1); g_adj[q] = i;
  }
}

// ---------------- img_features [B,C,H,W] f32 -> [B,H,W,C] bf16 ----------------
__global__ __launch_bounds__(256) void k_transpose(const float* __restrict__ feat){
  int idx = blockIdx.x*256 + threadIdx.x;
  int c = idx & (C_-1);
  int p = idx >> 7;            // (b*H + y)*W + x
  int x = p % W_;
  int q = p / W_;
  int y = q % H_;
  int b = q / H_;
  g_bhwc[idx] = (uint16_t)f2bf(feat[(((size_t)b*C_ + c)*H_ + y)*W_ + x]);
}

// ---------------- weights f32 -> MFMA A-operand fragment order (bf16) ----------------
// frag element (nt,ks,lane,j) = W[k = ks*32 + (lane>>4)*8 + j][n = nt*16 + (lane&15)]
__global__ void k_wprep(const float* w0,const float* w1,const float* w2,
                        const float* w3,const float* w4,const float* w5){
  int tid = blockIdx.x*256 + threadIdx.x;   // 12288 threads total
  int lane = tid & 63;
  int ks = (tid>>6)&3;
  int nt = (tid>>8)&7;
  int mat = tid>>11;
  const float* wsrc = w0;
  switch(mat){ case 1: wsrc=w1; break; case 2: wsrc=w2; break;
               case 3: wsrc=w3; break; case 4: wsrc=w4; break;
               case 5: wsrc=w5; break; default: break; }
  int n  = nt*16 + (lane&15);
  int kb = ks*32 + ((lane>>4)&3)*8;
  uint4 o;
  o.x = pk2(wsrc[(kb+0)*C_+n], wsrc[(kb+1)*C_+n]);
  o.y = pk2(wsrc[(kb+2)*C_+n], wsrc[(kb+3)*C_+n]);
  o.z = pk2(wsrc[(kb+4)*C_+n], wsrc[(kb+5)*C_+n]);
  o.w = pk2(wsrc[(kb+6)*C_+n], wsrc[(kb+7)*C_+n]);
  *(uint4*)&g_wf[mat][((nt*4+ks)*64+lane)*8] = o;
}

// ---------------- vert_align + vertex_padded -> g (bufA, [V,B,C] bf16) ----------------
__global__ __launch_bounds__(256) void k_vertalign(const float* __restrict__ vpos,
                                                   const float* __restrict__ vpad){
  int wid = blockIdx.x*4 + (threadIdx.x>>6);  // one wave per (v,b)
  int lane = threadIdx.x & 63;
  int v = wid >> 4, b = wid & 15;
  float px = vpos[((size_t)b*V_+v)*3 + 0];
  float py = vpos[((size_t)b*V_+v)*3 + 1];
  float fx = (px+1.f)*0.5f*(float)(W_-1);
  float fy = (py+1.f)*0.5f*(float)(H_-1);
  float x0f = floorf(fx), y0f = floorf(fy);
  float wx1 = fx-x0f, wy1 = fy-y0f;
  float wx0 = 1.f-wx1, wy0 = 1.f-wy1;
  int x0 = (int)x0f, y0 = (int)y0f;
  int c0 = lane*2;
  float a0 = 0.f, a1 = 0.f;
  #pragma unroll
  for (int t=0;t<4;++t){
    int xi = x0 + (t&1), yi = y0 + (t>>1);
    float wt = ((t&1)? wx1 : wx0) * ((t>>1)? wy1 : wy0);
    if (xi<0||xi>=W_||yi<0||yi>=H_) wt = 0.f;   // zero-pad via weight (matches ref)
    int xc = min(max(xi,0),W_-1), yc = min(max(yi,0),H_-1);
    uint32_t u = *(const uint32_t*)(g_bhwc + ((size_t)(b*H_+yc)*W_ + xc)*C_ + c0);
    a0 += bf_lo(u)*wt; a1 += bf_hi(u)*wt;
  }
  float2 vp = *(const float2*)(vpad + ((size_t)b*V_+v)*C_ + c0);
  a0 += vp.x;
  a1 += vp.y;
  *(uint32_t*)(g_bufA + ((size_t)v*B_+b)*C_ + c0) = pk2(a0,a1);
}

// ---------------- z = A * x (CSR gather, no atomics) -> bufB ----------------
__global__ __launch_bounds__(256) void k_aggregate(int xsel){
  const uint16_t* __restrict__ x = big_buf(xsel);
  int v = blockIdx.x;
  int t = threadIdx.x;
  int beg = g_rowptr[v], end = g_rowptr[v+1];
  float a0=0,a1=0,a2=0,a3=0,a4=0,a5=0,a6=0,a7=0;
  const size_t off = (size_t)t*8;
  for (int p=beg;p<end;++p){
    int j = g_adj[p];
    uint4 u = *(const uint4*)(x + (size_t)j*(B_*C_) + off);
    a0 += bf_lo(u.x); a1 += bf_hi(u.x);
    a2 += bf_lo(u.y); a3 += bf_hi(u.y);
    a4 += bf_lo(u.z); a5 += bf_hi(u.z);
    a6 += bf_lo(u.w); a7 += bf_hi(u.w);
  }
  uint4 o = { pk2(a0,a1), pk2(a2,a3), pk2(a4,a5), pk2(a6,a7) };
  *(uint4*)(g_bufB + (size_t)v*(B_*C_) + off) = o;
}

// ---------------- fused dual GEMM: out = x@W0 + z@W1 + b0 (+d for final) ----------------
// Weights as MFMA A-operand (W^T tiles) so D holds 4 consecutive out-channels per lane.
union FragCvt { uint4 u; bf16x8 v; };

__global__ __launch_bounds__(256,2) void k_gemm(int conv, int xsel,
                                                const float* __restrict__ bias_f,
                                                int osel, float* __restrict__ outf){
  __shared__ uint16_t lds_w[2*C_*C_];   // 64 KB: both weight matrices, frag-ordered
  const uint16_t* __restrict__ x  = big_buf(xsel);
  const uint16_t* __restrict__ zp = g_bufB;
  {
    const uint4* src = (const uint4*)(&g_wf[2*conv][0]);
    uint4* dst = (uint4*)lds_w;
    #pragma unroll
    for (int i=0;i<16;++i) dst[i*256 + threadIdx.x] = src[i*256 + threadIdx.x];
  }
  __syncthreads();
  const int wv = threadIdx.x>>6, lane = threadIdx.x&63;
  const int quad = lane>>4, l15 = lane&15;
  const int mbase = blockIdx.x*128 + wv*32;   // 2 m-tiles of 16 rows per wave

  FragCvt xf[2][4], zf[2][4];
  #pragma unroll
  for (int mt=0;mt<2;++mt)
    #pragma unroll
    for (int ks=0;ks<4;++ks){
      int row = mbase + mt*16 + l15;
      size_t ad = (size_t)row*C_ + ks*32 + quad*8;
      xf[mt][ks].u = *(const uint4*)(x  + ad);
      zf[mt][ks].u = *(const uint4*)(zp + ad);
    }
  f32x4 acc[2][8];
  #pragma unroll
  for (int mt=0;mt<2;++mt)
    #pragma unroll
    for (int nt=0;nt<8;++nt) acc[mt][nt] = (f32x4){0.f,0.f,0.f,0.f};

  const uint16_t* lw0 = lds_w;
  const uint16_t* lw1 = lds_w + C_*C_;
  #pragma unroll
  for (int nt=0;nt<8;++nt){
    #pragma unroll
    for (int ks=0;ks<4;++ks){
      FragCvt w0f, w1f;
      w0f.u = *(const uint4*)&lw0[((nt*4+ks)*64+lane)*8];
      w1f.u = *(const uint4*)&lw1[((nt*4+ks)*64+lane)*8];
      acc[0][nt] = __builtin_amdgcn_mfma_f32_16x16x32_bf16(w0f.v, xf[0][ks].v, acc[0][nt], 0,0,0);
      acc[0][nt] = __builtin_amdgcn_mfma_f32_16x16x32_bf16(w1f.v, zf[0][ks].v, acc[0][nt], 0,0,0);
      acc[1][nt] = __builtin_amdgcn_mfma_f32_16x16x32_bf16(w0f.v, xf[1][ks].v, acc[1][nt], 0,0,0);
      acc[1][nt] = __builtin_amdgcn_mfma_f32_16x16x32_bf16(w1f.v, zf[1][ks].v, acc[1][nt], 0,0,0);
    }
  }
  uint16_t* oint = big_buf(osel==3 ? 0 : osel);  // dummy for osel==3
  #pragma unroll
  for (int mt=0;mt<2;++mt){
    int mrow = mbase + mt*16 + l15;
    int vv = (mbase + mt*16) >> 4;       // B_==16: one m-tile == one vertex, all batches
    #pragma unroll
    for (int nt=0;nt<8;++nt){
      int colb = nt*16 + quad*4;
      f32x4 bu = *(const f32x4*)(bias_f + colb);
      float r0 = acc[mt][nt][0] + bu[0];
      float r1 = acc[mt][nt][1] + bu[1];
      float r2 = acc[mt][nt][2] + bu[2];
      float r3 = acc[mt][nt][3] + bu[3];
      if (osel==3){
        // final: += d residual (bf16), write f32 [B,V,C]
        uint2 du = *(const uint2*)(g_bufD + (size_t)mrow*C_ + colb);
        r0 += bf_lo(du.x); r1 += bf_hi(du.x); r2 += bf_lo(du.y); r3 += bf_hi(du.y);
        f32x4 o = { r0, r1, r2, r3 };
        *(f32x4*)(outf + ((size_t)l15*V_ + vv)*C_ + colb) = o;   // b = l15
      } else {
        uint2 o = { pk2(r0,r1), pk2(r2,r3) };
        *(uint2*)(oint + (size_t)mrow*C_ + colb) = o;            // [V,B,C] bf16 internal
      }
    }
  }
}

extern "C" void kernel_launch(void* const* d_in, const int* in_sizes, int n_in,
                              void* d_out, int out_size, void* d_ws, size_t ws_size,
                              hipStream_t stream) {
  const float* feat = (const float*)d_in[0];
  const float* vpos = (const float*)d_in[1];
  const float* vpad = (const float*)d_in[2];
  const int*   edges= (const int*)d_in[3];
  const float* w0_1 = (const float*)d_in[4];
  const float* b0_1 = (const float*)d_in[5];
  const float* w1_1 = (const float*)d_in[6];
  const float* w0_2 = (const float*)d_in[7];
  const float* b0_2 = (const float*)d_in[8];
  const float* w1_2 = (const float*)d_in[9];
  const float* w0_3 = (const float*)d_in[10];
  const float* b0_3 = (const float*)d_in[11];
  const float* w1_3 = (const float*)d_in[12];
  float* outp = (float*)d_out;

  hipLaunchKernelGGL(k_zero,      dim3((V_+255)/256), dim3(256), 0, stream);
  hipLaunchKernelGGL(k_count,     dim3((E_+255)/256), dim3(256), 0, stream, edges);
  hipLaunchKernelGGL(k_scan,      dim3(1),            dim3(1024),0, stream);
  hipLaunchKernelGGL(k_fill,      dim3((E_+255)/256), dim3(256), 0, stream, edges);
  hipLaunchKernelGGL(k_transpose, dim3((B_*H_*W_*C_)/256), dim3(256), 0, stream, feat);
  hipLaunchKernelGGL(k_wprep,     dim3(48),           dim3(256), 0, stream,
                     w0_1, w1_1, w0_2, w1_2, w0_3, w1_3);
  hipLaunchKernelGGL(k_vertalign, dim3(M_/4),         dim3(256), 0, stream, vpos, vpad);
  // conv1: g (bufA) -> d (bufD)
  hipLaunchKernelGGL(k_aggregate, dim3(V_),   dim3(256), 0, stream, 0);
  hipLaunchKernelGGL(k_gemm,      dim3(M_/128), dim3(256), 0, stream, 0, 0, b0_1, 2, outp);
  // conv2: d (bufD) -> t (bufA)
  hipLaunchKernelGGL(k_aggregate, dim3(V_),   dim3(256), 0, stream, 2);
  hipLaunchKernelGGL(k_gemm,      dim3(M_/128), dim3(256), 0, stream, 1, 2, b0_2, 0, outp);
  // conv3: t (bufA) -> out ([B,V,C] f32) with +d residual
  hipLaunchKernelGGL(k_aggregate, dim3(V_),   dim3(256), 0, stream, 0);
  hipLaunchKernelGGL(k_gemm,      dim3(M_/128), dim3(256), 0, stream, 2, 0, b0_3, 3, outp);
}